// Round 4
// baseline (6857.240 us; speedup 1.0000x reference)
//
#include <hip/hip_runtime.h>
#include <hip/hip_bf16.h>

#define TT   2048
#define BB   512
#define IN_  27
#define HH   64
#define NG   256   // 4*H
#define OUTD 26
#define EPSV 1e-5f

__device__ __forceinline__ float sigm(float x) {
    return 1.0f / (1.0f + __expf(-x));
}

__device__ __forceinline__ float tanh_fast(float x) {
    float e = __expf(-2.0f * fabsf(x));
    float r = (1.0f - e) / (1.0f + e);
    return copysignf(r, x);
}

// Opaque register pin: volatile asm cannot be sunk into the loop, duplicated,
// or rematerialized -> the 64 W_hh values are FORCED to stay in VGPRs.
// (R1/R3 evidence: VGPR_Count=56 both rounds — the backend was sinking the
// loop-invariant weight loads back into the loop body.)
#define PIN16(a,b,c,d,e,f,g,h,i,jj,k,ll,m,n,o,p) \
    asm volatile("" : "+v"(a),"+v"(b),"+v"(c),"+v"(d),"+v"(e),"+v"(f),"+v"(g),"+v"(h), \
                      "+v"(i),"+v"(jj),"+v"(k),"+v"(ll),"+v"(m),"+v"(n),"+v"(o),"+v"(p));

// Phase 0: gate_x[t,b,j] = b_ih[j] + b_hh[j] + W_ih[j,:].x[t,b,:]
// Fully t-parallel; removes the x-GEMM from the sequential critical path.
// One block = one timestep x 8 batch elements.
__global__ __launch_bounds__(256) void gate_x_pre(
    const float* __restrict__ x,     // [T,B,IN]
    const float* __restrict__ W_ih,  // [NG,IN]
    const float* __restrict__ b_ih,
    const float* __restrict__ b_hh,
    float* __restrict__ gate_x,      // [tc,BB,NG]
    int t0, int tc)
{
    const int j  = threadIdx.x;
    const int tl = blockIdx.x;
    const int bg = blockIdx.y;       // 8 batch elems per block
    const float bias = b_ih[j] + b_hh[j];
    const float* wr = W_ih + (size_t)j * IN_;

#pragma unroll
    for (int bb8 = 0; bb8 < 8; ++bb8) {
        const int b = bg * 8 + bb8;
        const float* xr = x + ((size_t)(t0 + tl) * BB + b) * IN_;  // wave-uniform
        float acc = bias;
#pragma unroll
        for (int k = 0; k < IN_; ++k) acc = fmaf(xr[k], wr[k], acc);
        gate_x[((size_t)tl * BB + b) * NG + j] = acc;
    }
}

// Phase 1: sequential LSTM. One block (256 thr) per batch element.
// thread = gate j (q = wave = i/f/g/o, l = h index). h broadcast via LDS
// (16x ds_read_b128, same-address broadcast = conflict-free) instead of
// 64 readlanes. W_hh row register-resident (pinned). c replicated per lane.
__global__ __launch_bounds__(256, 2) void lstm_seq(
    const float* __restrict__ gate_x,  // [tc,BB,NG]
    const float* __restrict__ W_hh,    // [NG,HH]
    float* __restrict__ h_all,         // [tc,BB,HH]
    float* __restrict__ state,         // [2,BB,HH]
    int tc, int first)
{
    const int b = blockIdx.x;
    const int j = threadIdx.x;
    const int q = j >> 6;        // 0=i 1=f 2=g 3=o (wave-uniform)
    const int l = j & 63;

    // --- W_hh row j -> 64 named, pinned floats ---
    const float4* whv = (const float4*)W_hh + (size_t)j * 16;
    float4 v0 = whv[0],  v1 = whv[1],  v2 = whv[2],  v3 = whv[3];
    float4 v4 = whv[4],  v5 = whv[5],  v6 = whv[6],  v7 = whv[7];
    float4 v8 = whv[8],  v9 = whv[9],  v10 = whv[10], v11 = whv[11];
    float4 v12 = whv[12], v13 = whv[13], v14 = whv[14], v15 = whv[15];
#define UNP(m, V) float wh##m##0=(V).x, wh##m##1=(V).y, wh##m##2=(V).z, wh##m##3=(V).w;
    UNP(0,v0) UNP(1,v1) UNP(2,v2) UNP(3,v3) UNP(4,v4) UNP(5,v5) UNP(6,v6) UNP(7,v7)
    UNP(8,v8) UNP(9,v9) UNP(10,v10) UNP(11,v11) UNP(12,v12) UNP(13,v13) UNP(14,v14) UNP(15,v15)
#undef UNP
    PIN16(wh00,wh01,wh02,wh03, wh10,wh11,wh12,wh13, wh20,wh21,wh22,wh23, wh30,wh31,wh32,wh33)
    PIN16(wh40,wh41,wh42,wh43, wh50,wh51,wh52,wh53, wh60,wh61,wh62,wh63, wh70,wh71,wh72,wh73)
    PIN16(wh80,wh81,wh82,wh83, wh90,wh91,wh92,wh93, wh100,wh101,wh102,wh103, wh110,wh111,wh112,wh113)
    PIN16(wh120,wh121,wh122,wh123, wh130,wh131,wh132,wh133, wh140,wh141,wh142,wh143, wh150,wh151,wh152,wh153)

    float cv, hcur;
    if (first) { cv = 0.0f; hcur = 0.0f; }
    else {
        hcur = state[b * HH + l];
        cv   = state[BB * HH + b * HH + l];
    }

    __shared__ float  acts[NG];
    __shared__ float4 hbuf[16];   // h[0..63]

    if (q == 0) ((float*)hbuf)[l] = hcur;
    __syncthreads();

    const float* gxp = gate_x + (size_t)b * NG + j;
    float gx = *gxp;

    for (int tl = 0; tl < tc; ++tl) {
        // prefetch next step's gate_x (coalesced 1 float/lane)
        const float* gxn = gxp + ((tl + 1 < tc) ? (size_t)BB * NG : 0);
        const float gx_n = *gxn;

        // gate = gx + W_hh[j,:].h  — h broadcast from LDS, 4 accumulators
        float a0 = gx, a1 = 0.0f, a2 = 0.0f, a3 = 0.0f;
#define HD(m) { float4 h4 = hbuf[m]; \
        a0 = fmaf(h4.x, wh##m##0, a0); \
        a1 = fmaf(h4.y, wh##m##1, a1); \
        a2 = fmaf(h4.z, wh##m##2, a2); \
        a3 = fmaf(h4.w, wh##m##3, a3); }
        HD(0) HD(1) HD(2) HD(3) HD(4) HD(5) HD(6) HD(7)
        HD(8) HD(9) HD(10) HD(11) HD(12) HD(13) HD(14) HD(15)
#undef HD
        const float acc = (a0 + a1) + (a2 + a3);

        const float av = (q == 2) ? tanh_fast(acc) : sigm(acc);
        acts[j] = av;
        __syncthreads();   // B1: acts visible

        const float gi = acts[l];
        const float gf = acts[HH + l];
        const float gg = acts[2 * HH + l];
        const float go = acts[3 * HH + l];

        const float cn = fmaf(gf, cv, gi * gg);
        const float hn = go * tanh_fast(cn);
        cv = cn;
        hcur = hn;

        if (q == 0) {
            ((float*)hbuf)[l] = hn;
            h_all[((size_t)tl * BB + b) * HH + l] = hn;
        }
        __syncthreads();   // B2: hbuf visible for next step
        gx = gx_n;
        gxp += (size_t)BB * NG;
    }

    if (q == 0) {
        state[b * HH + l] = hcur;
        state[BB * HH + b * HH + l] = cv;
    }
}

// Phase 2: per-timestep BatchNorm (batch stats) + locked dropout + maxpool
// over batch + FC. One block per timestep, fully parallel.
__global__ __launch_bounds__(256, 2) void bn_pool_fc(
    const float* __restrict__ h_all,  // [tc,B,H]
    const float* __restrict__ gamma,
    const float* __restrict__ beta,
    const float* __restrict__ dmask,  // [B,H]
    const float* __restrict__ pg,     // [T,OUT]
    const float* __restrict__ W_fc,   // [OUT, H+OUT]
    const float* __restrict__ b_fc,
    float* __restrict__ y,            // [T,OUT]
    int t0, int tc)
{
    const int tl = blockIdx.x;
    const int t = t0 + tl;
    const int tid = threadIdx.x;
    const int g = tid >> 6;
    const int hcol = tid & 63;
    const float* hp = h_all + (size_t)tl * BB * HH;

    __shared__ float s_a[4][HH];
    __shared__ float s_b[4][HH];
    __shared__ float s_scale[HH];
    __shared__ float s_shift[HH];
    __shared__ float s_pool[HH];

    float sum = 0.0f, sq = 0.0f;
    for (int bb = g; bb < BB; bb += 4) {
        const float v = hp[bb * HH + hcol];
        sum += v;
        sq = fmaf(v, v, sq);
    }
    s_a[g][hcol] = sum;
    s_b[g][hcol] = sq;
    __syncthreads();

    if (tid < HH) {
        const float s  = (s_a[0][tid] + s_a[1][tid]) + (s_a[2][tid] + s_a[3][tid]);
        const float q2 = (s_b[0][tid] + s_b[1][tid]) + (s_b[2][tid] + s_b[3][tid]);
        const float mean = s * (1.0f / BB);
        const float var  = q2 * (1.0f / BB) - mean * mean;
        const float rs = rsqrtf(var + EPSV);
        const float sc = rs * gamma[tid];
        s_scale[tid] = sc;
        s_shift[tid] = beta[tid] - mean * sc;
    }
    __syncthreads();

    const float sc = s_scale[hcol];
    const float sh = s_shift[hcol];
    float m = -3.0e38f;
    for (int bb = g; bb < BB; bb += 4) {
        const float v = hp[bb * HH + hcol];
        const float hd = fmaf(v, sc, sh) * dmask[bb * HH + hcol];
        m = fmaxf(m, hd);
    }
    s_a[g][hcol] = m;
    __syncthreads();
    if (tid < HH) {
        s_pool[tid] = fmaxf(fmaxf(s_a[0][tid], s_a[1][tid]),
                            fmaxf(s_a[2][tid], s_a[3][tid]));
    }
    __syncthreads();

    if (tid < OUTD) {
        float acc = b_fc[tid];
        const float* w = W_fc + tid * (HH + OUTD);
#pragma unroll
        for (int k = 0; k < HH; ++k) acc = fmaf(w[k], s_pool[k], acc);
#pragma unroll
        for (int k = 0; k < OUTD; ++k) acc = fmaf(w[HH + k], pg[t * OUTD + k], acc);
        y[t * OUTD + tid] = acc;
    }
}

extern "C" void kernel_launch(void* const* d_in, const int* in_sizes, int n_in,
                              void* d_out, int out_size, void* d_ws, size_t ws_size,
                              hipStream_t stream)
{
    const float* x     = (const float*)d_in[0];
    const float* pg    = (const float*)d_in[1];
    const float* W_ih  = (const float*)d_in[2];
    const float* W_hh  = (const float*)d_in[3];
    const float* b_ih  = (const float*)d_in[4];
    const float* b_hh  = (const float*)d_in[5];
    const float* gamma = (const float*)d_in[6];
    const float* beta  = (const float*)d_in[7];
    const float* W_fc  = (const float*)d_in[8];
    const float* b_fc  = (const float*)d_in[9];
    const float* dmask = (const float*)d_in[10];
    float* y = (float*)d_out;

    // ws layout: h_all[chunkT,B,H] | gate_x[chunkT,B,NG] | state[2,B,H]
    const size_t state_bytes = 2ull * BB * HH * sizeof(float);
    const size_t per_t = (size_t)BB * HH * sizeof(float) + (size_t)BB * NG * sizeof(float);
    size_t avail = (ws_size > state_bytes) ? (ws_size - state_bytes) : 0;
    int chunkT = (int)(avail / per_t);
    if (chunkT > TT) chunkT = TT;
    if (chunkT < 1) chunkT = 1;

    float* h_all  = (float*)d_ws;
    float* gate_x = h_all + (size_t)chunkT * BB * HH;
    float* state  = gate_x + (size_t)chunkT * BB * NG;

    int first = 1;
    for (int t0 = 0; t0 < TT; t0 += chunkT) {
        int tc = TT - t0;
        if (tc > chunkT) tc = chunkT;
        gate_x_pre<<<dim3(tc, BB / 8), 256, 0, stream>>>(x, W_ih, b_ih, b_hh,
                                                         gate_x, t0, tc);
        lstm_seq<<<BB, 256, 0, stream>>>(gate_x, W_hh, h_all, state, tc, first);
        bn_pool_fc<<<tc, 256, 0, stream>>>(h_all, gamma, beta, dmask, pg,
                                           W_fc, b_fc, y, t0, tc);
        first = 0;
    }
}

// Round 5
// 2365.607 us; speedup vs baseline: 2.8987x; 2.8987x over previous
//
#include <hip/hip_runtime.h>
#include <hip/hip_bf16.h>

#define TT   2048
#define BB   512
#define IN_  27
#define HH   64
#define NG   256   // 4*H
#define OUTD 26
#define EPSV 1e-5f
#define RT   64    // rows per gate_x_pre block

__device__ __forceinline__ float sigm(float x) {
    return 1.0f / (1.0f + __expf(-x));
}

__device__ __forceinline__ float tanh_fast(float x) {
    float e = __expf(-2.0f * fabsf(x));
    float r = (1.0f - e) / (1.0f + e);
    return copysignf(r, x);
}

// Opaque register pin: volatile asm cannot be sunk/rematerialized -> values
// are FORCED live in VGPRs (R1/R3: backend sank loop-invariant weight loads).
#define PIN16(a,b,c,d,e,f,g,h,i,jj,k,ll,m,n,o,p) \
    asm volatile("" : "+v"(a),"+v"(b),"+v"(c),"+v"(d),"+v"(e),"+v"(f),"+v"(g),"+v"(h), \
                      "+v"(i),"+v"(jj),"+v"(k),"+v"(ll),"+v"(m),"+v"(n),"+v"(o),"+v"(p));

// Phase 0 (rewritten R5): gate_x[row, j] = b_ih[j]+b_hh[j] + W_ih[j,:].x[row,:]
// row = t*B+b flat. LDS-tiled skinny GEMM: W_ih staged padded (28) once per
// block, x tile (64 contiguous rows) staged coalesced, inner loop reads x via
// broadcast ds_read_b128. Stores fully coalesced (1 KB/wave/row).
__global__ __launch_bounds__(256, 4) void gate_x_pre(
    const float* __restrict__ x,     // [T*B, IN]
    const float* __restrict__ W_ih,  // [NG, IN]
    const float* __restrict__ b_ih,
    const float* __restrict__ b_hh,
    float* __restrict__ gate_x,      // [nrows, NG] (chunk-local)
    int row0, int nrows)
{
    const int j = threadIdx.x;
    __shared__ float w_s[NG * 28];   // 28.7 KB, rows padded 27->28 (112 B, 16B-aligned)
    __shared__ float x_s[RT * 28];   // 7.2 KB

    // stage W_ih (6912 floats, coalesced read; padded LDS write)
#pragma unroll
    for (int s = 0; s < 27; ++s) {
        const int idx = j + s * 256;          // 0..6911
        const int r = idx / 27;
        const int c = idx - r * 27;
        w_s[r * 28 + c] = W_ih[idx];
    }
    // stage x tile: 64 rows are CONTIGUOUS in x (row-flat layout) -> coalesced
    const int rbase = blockIdx.x * RT;        // chunk-local row
    const float* xsrc = x + (size_t)(row0 + rbase) * IN_;
#pragma unroll
    for (int s = 0; s < 7; ++s) {
        const int idx = j + s * 256;
        if (idx < RT * IN_) {
            const int r = idx / 27;
            const int c = idx - r * 27;
            x_s[r * 28 + c] = xsrc[idx];
        }
    }
    __syncthreads();

    // W row j -> 7 named float4 (28 floats; element 27 is pad, never used)
    const float4* wr4 = (const float4*)(w_s + j * 28);
    float4 q0 = wr4[0], q1 = wr4[1], q2 = wr4[2], q3 = wr4[3];
    float4 q4 = wr4[4], q5 = wr4[5], q6 = wr4[6];
    const float bias = b_ih[j] + b_hh[j];

    float* out = gate_x + (size_t)rbase * NG + j;
#pragma unroll 4
    for (int r = 0; r < RT; ++r) {
        const float4* xr4 = (const float4*)(x_s + r * 28);  // uniform addr -> broadcast
        const float4 p0 = xr4[0], p1 = xr4[1], p2 = xr4[2], p3 = xr4[3];
        const float4 p4 = xr4[4], p5 = xr4[5], p6 = xr4[6];
        float a0 = bias, a1 = 0.0f, a2 = 0.0f, a3 = 0.0f;
        a0 = fmaf(q0.x, p0.x, a0); a1 = fmaf(q0.y, p0.y, a1);
        a2 = fmaf(q0.z, p0.z, a2); a3 = fmaf(q0.w, p0.w, a3);
        a0 = fmaf(q1.x, p1.x, a0); a1 = fmaf(q1.y, p1.y, a1);
        a2 = fmaf(q1.z, p1.z, a2); a3 = fmaf(q1.w, p1.w, a3);
        a0 = fmaf(q2.x, p2.x, a0); a1 = fmaf(q2.y, p2.y, a1);
        a2 = fmaf(q2.z, p2.z, a2); a3 = fmaf(q2.w, p2.w, a3);
        a0 = fmaf(q3.x, p3.x, a0); a1 = fmaf(q3.y, p3.y, a1);
        a2 = fmaf(q3.z, p3.z, a2); a3 = fmaf(q3.w, p3.w, a3);
        a0 = fmaf(q4.x, p4.x, a0); a1 = fmaf(q4.y, p4.y, a1);
        a2 = fmaf(q4.z, p4.z, a2); a3 = fmaf(q4.w, p4.w, a3);
        a0 = fmaf(q5.x, p5.x, a0); a1 = fmaf(q5.y, p5.y, a1);
        a2 = fmaf(q5.z, p5.z, a2); a3 = fmaf(q5.w, p5.w, a3);
        a0 = fmaf(q6.x, p6.x, a0); a1 = fmaf(q6.y, p6.y, a1);
        a2 = fmaf(q6.z, p6.z, a2);   // skip .w (pad)
        out[(size_t)r * NG] = (a0 + a1) + (a2 + a3);
    }
}

// Phase 1: sequential LSTM. One block (256 thr) per batch element.
// thread = gate j (q = wave = i/f/g/o, l = h index). h broadcast via LDS.
// W_hh row register-resident (pinned). gate_x prefetched at DISTANCE 2 to
// cover ~900 cyc HBM latency (R4: distance-1 left ~half the latency exposed).
__global__ __launch_bounds__(256, 2) void lstm_seq(
    const float* __restrict__ gate_x,  // [tc*BB, NG]
    const float* __restrict__ W_hh,    // [NG,HH]
    float* __restrict__ h_all,         // [tc,BB,HH]
    float* __restrict__ state,         // [2,BB,HH]
    int tc, int first)
{
    const int b = blockIdx.x;
    const int j = threadIdx.x;
    const int q = j >> 6;
    const int l = j & 63;

    const float4* whv = (const float4*)W_hh + (size_t)j * 16;
    float4 v0 = whv[0],  v1 = whv[1],  v2 = whv[2],  v3 = whv[3];
    float4 v4 = whv[4],  v5 = whv[5],  v6 = whv[6],  v7 = whv[7];
    float4 v8 = whv[8],  v9 = whv[9],  v10 = whv[10], v11 = whv[11];
    float4 v12 = whv[12], v13 = whv[13], v14 = whv[14], v15 = whv[15];
#define UNP(m, V) float wh##m##0=(V).x, wh##m##1=(V).y, wh##m##2=(V).z, wh##m##3=(V).w;
    UNP(0,v0) UNP(1,v1) UNP(2,v2) UNP(3,v3) UNP(4,v4) UNP(5,v5) UNP(6,v6) UNP(7,v7)
    UNP(8,v8) UNP(9,v9) UNP(10,v10) UNP(11,v11) UNP(12,v12) UNP(13,v13) UNP(14,v14) UNP(15,v15)
#undef UNP
    PIN16(wh00,wh01,wh02,wh03, wh10,wh11,wh12,wh13, wh20,wh21,wh22,wh23, wh30,wh31,wh32,wh33)
    PIN16(wh40,wh41,wh42,wh43, wh50,wh51,wh52,wh53, wh60,wh61,wh62,wh63, wh70,wh71,wh72,wh73)
    PIN16(wh80,wh81,wh82,wh83, wh90,wh91,wh92,wh93, wh100,wh101,wh102,wh103, wh110,wh111,wh112,wh113)
    PIN16(wh120,wh121,wh122,wh123, wh130,wh131,wh132,wh133, wh140,wh141,wh142,wh143, wh150,wh151,wh152,wh153)

    float cv, hcur;
    if (first) { cv = 0.0f; hcur = 0.0f; }
    else {
        hcur = state[b * HH + l];
        cv   = state[BB * HH + b * HH + l];
    }

    __shared__ float  acts[NG];
    __shared__ float4 hbuf[16];

    if (q == 0) ((float*)hbuf)[l] = hcur;
    __syncthreads();

    const size_t stride = (size_t)BB * NG;
    const float* gbase = gate_x + (size_t)b * NG + j;

    // distance-2 pipeline
    float gx0 = gbase[0];
    float gx1 = (tc > 1) ? gbase[stride] : gx0;

    for (int tl = 0; tl < tc; ++tl) {
        const int t2 = (tl + 2 < tc) ? (tl + 2) : (tc - 1);
        const float gx2 = gbase[(size_t)t2 * stride];   // issues ~2 steps early

        float a0 = gx0, a1 = 0.0f, a2 = 0.0f, a3 = 0.0f;
#define HD(m) { float4 h4 = hbuf[m]; \
        a0 = fmaf(h4.x, wh##m##0, a0); \
        a1 = fmaf(h4.y, wh##m##1, a1); \
        a2 = fmaf(h4.z, wh##m##2, a2); \
        a3 = fmaf(h4.w, wh##m##3, a3); }
        HD(0) HD(1) HD(2) HD(3) HD(4) HD(5) HD(6) HD(7)
        HD(8) HD(9) HD(10) HD(11) HD(12) HD(13) HD(14) HD(15)
#undef HD
        const float acc = (a0 + a1) + (a2 + a3);

        const float av = (q == 2) ? tanh_fast(acc) : sigm(acc);
        acts[j] = av;
        __syncthreads();   // B1: acts visible

        const float gi = acts[l];
        const float gf = acts[HH + l];
        const float gg = acts[2 * HH + l];
        const float go = acts[3 * HH + l];

        const float cn = fmaf(gf, cv, gi * gg);
        const float hn = go * tanh_fast(cn);
        cv = cn;
        hcur = hn;

        if (q == 0) {
            ((float*)hbuf)[l] = hn;
            h_all[((size_t)tl * BB + b) * HH + l] = hn;
        }
        __syncthreads();   // B2: hbuf visible for next step
        gx0 = gx1;
        gx1 = gx2;
    }

    if (q == 0) {
        state[b * HH + l] = hcur;
        state[BB * HH + b * HH + l] = cv;
    }
}

// Phase 2: per-timestep BatchNorm (batch stats) + locked dropout + maxpool
// over batch + FC. One block per timestep, fully parallel.
__global__ __launch_bounds__(256, 2) void bn_pool_fc(
    const float* __restrict__ h_all,  // [tc,B,H]
    const float* __restrict__ gamma,
    const float* __restrict__ beta,
    const float* __restrict__ dmask,  // [B,H]
    const float* __restrict__ pg,     // [T,OUT]
    const float* __restrict__ W_fc,   // [OUT, H+OUT]
    const float* __restrict__ b_fc,
    float* __restrict__ y,            // [T,OUT]
    int t0, int tc)
{
    const int tl = blockIdx.x;
    const int t = t0 + tl;
    const int tid = threadIdx.x;
    const int g = tid >> 6;
    const int hcol = tid & 63;
    const float* hp = h_all + (size_t)tl * BB * HH;

    __shared__ float s_a[4][HH];
    __shared__ float s_b[4][HH];
    __shared__ float s_scale[HH];
    __shared__ float s_shift[HH];
    __shared__ float s_pool[HH];

    float sum = 0.0f, sq = 0.0f;
    for (int bb = g; bb < BB; bb += 4) {
        const float v = hp[bb * HH + hcol];
        sum += v;
        sq = fmaf(v, v, sq);
    }
    s_a[g][hcol] = sum;
    s_b[g][hcol] = sq;
    __syncthreads();

    if (tid < HH) {
        const float s  = (s_a[0][tid] + s_a[1][tid]) + (s_a[2][tid] + s_a[3][tid]);
        const float q2 = (s_b[0][tid] + s_b[1][tid]) + (s_b[2][tid] + s_b[3][tid]);
        const float mean = s * (1.0f / BB);
        const float var  = q2 * (1.0f / BB) - mean * mean;
        const float rs = rsqrtf(var + EPSV);
        const float sc = rs * gamma[tid];
        s_scale[tid] = sc;
        s_shift[tid] = beta[tid] - mean * sc;
    }
    __syncthreads();

    const float sc = s_scale[hcol];
    const float sh = s_shift[hcol];
    float m = -3.0e38f;
    for (int bb = g; bb < BB; bb += 4) {
        const float v = hp[bb * HH + hcol];
        const float hd = fmaf(v, sc, sh) * dmask[bb * HH + hcol];
        m = fmaxf(m, hd);
    }
    s_a[g][hcol] = m;
    __syncthreads();
    if (tid < HH) {
        s_pool[tid] = fmaxf(fmaxf(s_a[0][tid], s_a[1][tid]),
                            fmaxf(s_a[2][tid], s_a[3][tid]));
    }
    __syncthreads();

    if (tid < OUTD) {
        float acc = b_fc[tid];
        const float* w = W_fc + tid * (HH + OUTD);
#pragma unroll
        for (int k = 0; k < HH; ++k) acc = fmaf(w[k], s_pool[k], acc);
#pragma unroll
        for (int k = 0; k < OUTD; ++k) acc = fmaf(w[HH + k], pg[t * OUTD + k], acc);
        y[t * OUTD + tid] = acc;
    }
}

extern "C" void kernel_launch(void* const* d_in, const int* in_sizes, int n_in,
                              void* d_out, int out_size, void* d_ws, size_t ws_size,
                              hipStream_t stream)
{
    const float* x     = (const float*)d_in[0];
    const float* pg    = (const float*)d_in[1];
    const float* W_ih  = (const float*)d_in[2];
    const float* W_hh  = (const float*)d_in[3];
    const float* b_ih  = (const float*)d_in[4];
    const float* b_hh  = (const float*)d_in[5];
    const float* gamma = (const float*)d_in[6];
    const float* beta  = (const float*)d_in[7];
    const float* W_fc  = (const float*)d_in[8];
    const float* b_fc  = (const float*)d_in[9];
    const float* dmask = (const float*)d_in[10];
    float* y = (float*)d_out;

    // ws layout: h_all[chunkT,B,H] | gate_x[chunkT,B,NG] | state[2,B,H]
    const size_t state_bytes = 2ull * BB * HH * sizeof(float);
    const size_t per_t = (size_t)BB * HH * sizeof(float) + (size_t)BB * NG * sizeof(float);
    size_t avail = (ws_size > state_bytes) ? (ws_size - state_bytes) : 0;
    int chunkT = (int)(avail / per_t);
    if (chunkT > TT) chunkT = TT;
    if (chunkT < 1) chunkT = 1;

    float* h_all  = (float*)d_ws;
    float* gate_x = h_all + (size_t)chunkT * BB * HH;
    float* state  = gate_x + (size_t)chunkT * BB * NG;

    int first = 1;
    for (int t0 = 0; t0 < TT; t0 += chunkT) {
        int tc = TT - t0;
        if (tc > chunkT) tc = chunkT;
        const int nrows = tc * BB;
        gate_x_pre<<<nrows / RT, 256, 0, stream>>>(x, W_ih, b_ih, b_hh,
                                                   gate_x, t0 * BB, nrows);
        lstm_seq<<<BB, 256, 0, stream>>>(gate_x, W_hh, h_all, state, tc, first);
        bn_pool_fc<<<tc, 256, 0, stream>>>(h_all, gamma, beta, dmask, pg,
                                           W_fc, b_fc, y, t0, tc);
        first = 0;
    }
}